// Round 2
// baseline (624.763 us; speedup 1.0000x reference)
//
#include <hip/hip_runtime.h>
#include <hip/hip_bf16.h>
#include <math.h>

// ---------------------------------------------------------------------------
// 2-layer GCN (PyG GCNConv semantics), fp32.
//   deg[i]   = 1 + sum_{e: dst[e]==i} w[e]          (self-loop weight 1)
//   dinv     = rsqrt(deg)
//   h1       = x @ W1                                [n,512]x[512,16]
//   agg1[i]  = dinv[i]^2 * h1[i] + sum_e dinv[s]*w*dinv[d] * h1[s]  (d==i)
//   h2       = relu(agg1 + b1) @ W2                  [n,16]x[16,8]
//   out[i]   = dinv[i]^2 * h2[i] + sum_e norm * h2[s]
//   out      = log_softmax(out + b2, axis=1)
//
// NOTE: harness delivers integer inputs as int32 (edge_index is int32 here,
// even though the reference uses int64).
// ---------------------------------------------------------------------------

__global__ void k_init_deg(float* __restrict__ deg, int n) {
    int i = blockIdx.x * blockDim.x + threadIdx.x;
    if (i < n) deg[i] = 1.0f;  // self-loop weight
}

__global__ void k_deg_scatter(const int* __restrict__ dst,
                              const float* __restrict__ w,
                              float* __restrict__ deg, int E) {
    int e = blockIdx.x * blockDim.x + threadIdx.x;
    if (e < E) atomicAdd(&deg[dst[e]], w[e]);
}

__global__ void k_rsqrt_inplace(float* __restrict__ deg, int n) {
    int i = blockIdx.x * blockDim.x + threadIdx.x;
    if (i < n) {
        float d = deg[i];
        deg[i] = d > 0.0f ? rsqrtf(d) : 0.0f;
    }
}

// h1 = x @ W1.  Block = 256 threads = 4 waves; each wave does 4 rows x 16 cols.
// Lane (c = lane&15, r = lane>>4). x read as float4 (16 lanes broadcast-share
// one address -> one coalesced transaction per row per iter; each x element
// read exactly once from HBM). W1^T staged in LDS, row stride 516 floats
// (padding breaks the stride-512 bank pattern; 516*4 bytes is 16B aligned).
__global__ __launch_bounds__(256) void k_gemm1(const float* __restrict__ x,
                                               const float* __restrict__ W1,
                                               float* __restrict__ h1, int n) {
    __shared__ float Wt[16 * 516];
    int tid = threadIdx.x;
    for (int idx = tid; idx < 512 * 16; idx += 256) {
        int k = idx >> 4, c = idx & 15;
        Wt[c * 516 + k] = W1[idx];
    }
    __syncthreads();
    int wave = tid >> 6, lane = tid & 63;
    int c = lane & 15, r = lane >> 4;
    int row = blockIdx.x * 16 + wave * 4 + r;
    if (row >= n) return;
    const float4* xr = (const float4*)(x + (size_t)row * 512);
    const float4* wr = (const float4*)(Wt + c * 516);
    float4 acc = make_float4(0.f, 0.f, 0.f, 0.f);
#pragma unroll 8
    for (int k4 = 0; k4 < 128; ++k4) {
        float4 xv = xr[k4];
        float4 wv = wr[k4];
        acc.x = fmaf(xv.x, wv.x, acc.x);
        acc.y = fmaf(xv.y, wv.y, acc.y);
        acc.z = fmaf(xv.z, wv.z, acc.z);
        acc.w = fmaf(xv.w, wv.w, acc.w);
    }
    h1[(size_t)row * 16 + c] = (acc.x + acc.y) + (acc.z + acc.w);
}

// agg[i*CH+c] = dinv[i]^2 * h[i*CH+c]   (the self-loop contribution)
template <int CH>
__global__ void k_self_init(const float* __restrict__ dinv,
                            const float* __restrict__ h,
                            float* __restrict__ agg, int n) {
    int t = blockIdx.x * blockDim.x + threadIdx.x;
    int i = t / CH;
    if (i < n) {
        float dv = dinv[i];
        agg[t] = dv * dv * h[t];
    }
}

// Edge scatter: CH consecutive lanes own one edge -> the CH atomics land in one
// (CH=16: 64B) cache line => TCC coalesces to a single line RMW per edge.
template <int CH>
__global__ void k_scatter(const int* __restrict__ src,
                          const int* __restrict__ dst,
                          const float* __restrict__ w,
                          const float* __restrict__ dinv,
                          const float* __restrict__ h,
                          float* __restrict__ agg, int E) {
    int t = blockIdx.x * blockDim.x + threadIdx.x;
    int e = t / CH;
    int c = t % CH;
    if (e >= E) return;
    int s = src[e];
    int d = dst[e];
    float nrm = dinv[s] * w[e] * dinv[d];
    atomicAdd(&agg[(size_t)d * CH + c], nrm * h[(size_t)s * CH + c]);
}

// h2 = relu(agg1 + b1) @ W2   [n,16]x[16,8]; 8 lanes per row.
__global__ __launch_bounds__(256) void k_gemm2(const float* __restrict__ agg1,
                                               const float* __restrict__ b1,
                                               const float* __restrict__ W2,
                                               float* __restrict__ h2, int n) {
    __shared__ float w2s[16 * 8];
    __shared__ float b1s[16];
    int tid = threadIdx.x;
    if (tid < 128) w2s[tid] = W2[tid];
    if (tid < 16) b1s[tid] = b1[tid];
    __syncthreads();
    int t = blockIdx.x * 256 + tid;
    int i = t >> 3, cc = t & 7;
    if (i >= n) return;
    const float* a = agg1 + (size_t)i * 16;
    float acc = 0.f;
#pragma unroll
    for (int k = 0; k < 16; ++k) {
        float v = fmaxf(a[k] + b1s[k], 0.f);
        acc = fmaf(v, w2s[k * 8 + cc], acc);
    }
    h2[(size_t)i * 8 + cc] = acc;
}

// In-place: out[i] = log_softmax(out[i] + b2)
__global__ void k_logsoftmax(float* __restrict__ out,
                             const float* __restrict__ b2, int n) {
    int i = blockIdx.x * blockDim.x + threadIdx.x;
    if (i >= n) return;
    float v[8];
#pragma unroll
    for (int c = 0; c < 8; ++c) v[c] = out[(size_t)i * 8 + c] + b2[c];
    float m = v[0];
#pragma unroll
    for (int c = 1; c < 8; ++c) m = fmaxf(m, v[c]);
    float s = 0.f;
#pragma unroll
    for (int c = 0; c < 8; ++c) s += expf(v[c] - m);
    float l = m + logf(s);
#pragma unroll
    for (int c = 0; c < 8; ++c) out[(size_t)i * 8 + c] = v[c] - l;
}

extern "C" void kernel_launch(void* const* d_in, const int* in_sizes, int n_in,
                              void* d_out, int out_size, void* d_ws, size_t ws_size,
                              hipStream_t stream) {
    const float* x   = (const float*)d_in[0];
    const int*   ei  = (const int*)d_in[1];     // int32 per harness convention
    const float* ew  = (const float*)d_in[2];
    const float* W1  = (const float*)d_in[3];
    const float* b1  = (const float*)d_in[4];
    const float* W2  = (const float*)d_in[5];
    const float* b2  = (const float*)d_in[6];
    float* out       = (float*)d_out;

    const int n = in_sizes[0] / 512;
    const int E = in_sizes[2];
    const int* src = ei;
    const int* dst = ei + E;

    // workspace: deg/dinv [n] | h1 [16n] (h2 [8n] aliases h1) | agg1 [16n]
    //          = 33n floats (~13.2 MB)
    float* deg  = (float*)d_ws;
    float* h1   = deg + n;
    float* h2   = h1;                       // h1 dead once agg1 is complete
    float* agg1 = h1 + (size_t)16 * n;

    const int B = 256;
    int gn = (n + B - 1) / B;

    k_init_deg<<<gn, B, 0, stream>>>(deg, n);
    k_deg_scatter<<<(E + B - 1) / B, B, 0, stream>>>(dst, ew, deg, E);
    k_rsqrt_inplace<<<gn, B, 0, stream>>>(deg, n);

    k_gemm1<<<(n + 15) / 16, B, 0, stream>>>(x, W1, h1, n);

    k_self_init<16><<<((size_t)16 * n + B - 1) / B, B, 0, stream>>>(deg, h1, agg1, n);
    k_scatter<16><<<((size_t)16 * E + B - 1) / B, B, 0, stream>>>(src, dst, ew, deg, h1, agg1, E);

    k_gemm2<<<((size_t)8 * n + B - 1) / B, B, 0, stream>>>(agg1, b1, W2, h2, n);

    k_self_init<8><<<((size_t)8 * n + B - 1) / B, B, 0, stream>>>(deg, h2, out, n);
    k_scatter<8><<<((size_t)8 * E + B - 1) / B, B, 0, stream>>>(src, dst, ew, deg, h2, out, E);

    k_logsoftmax<<<gn, B, 0, stream>>>(out, b2, n);
}